// Round 9
// baseline (827.962 us; speedup 1.0000x reference)
//
#include <hip/hip_runtime.h>
#include <hip/hip_bf16.h>

#define IN_DIM 128
#define OUT_DIM 64
#define NPB_LOG 7                  // 128 nodes per bucket
#define NPB (1 << NPB_LOG)
#define MAXBUCK 1024               // supports n_nodes <= 128K
#define B1 512                     // bucketing blocks (kA/kB); must match
#define ACC_STRIDE 65              // LDS accumulator stride (bank-conflict pad)

static inline size_t align_up(size_t v, size_t a) { return (v + a - 1) & ~(a - 1); }

__device__ __forceinline__ float bf2f(unsigned short u) {
    return __uint_as_float(((unsigned int)u) << 16);
}
__device__ __forceinline__ unsigned short f2bf(float f) {
    unsigned int x = __float_as_uint(f);
    unsigned int r = (x + 0x7fffu + ((x >> 16) & 1u)) >> 16;  // RTNE
    return (unsigned short)r;
}

typedef _Float16 half8 __attribute__((ext_vector_type(8)));
typedef float f32x4 __attribute__((ext_vector_type(4)));

// ---------------------------------------------------------------------------
// kA': per-block LDS histogram of col>>7 + global ticket atomics.
// tickets[blk][bin] = this block's exclusive offset within bin (order-free);
// BinTotal[bin] accumulates the final per-bucket edge counts.
// Replaces the old kA + kS1 pair.
// ---------------------------------------------------------------------------
__global__ void __launch_bounds__(256) kA_ticket(
    const int* __restrict__ col, int* __restrict__ BinTotal,
    int* __restrict__ tickets, int n_edges, int nbuck, int chunk) {
    __shared__ int hist[MAXBUCK];
    int t = threadIdx.x;
    for (int i = t; i < nbuck; i += 256) hist[i] = 0;
    __syncthreads();
    int start = blockIdx.x * chunk;
    int end = min(n_edges, start + chunk);
    for (int i = start + t; i < end; i += 256)
        atomicAdd(&hist[col[i] >> NPB_LOG], 1);
    __syncthreads();
    int* trow = tickets + (size_t)blockIdx.x * nbuck;
    for (int i = t; i < nbuck; i += 256) {
        int cv = hist[i];
        trow[i] = atomicAdd(&BinTotal[i], cv);  // returns exclusive base
    }
}

// ---------------------------------------------------------------------------
// kS2: exclusive scan of BinTotal -> BucketStart[nbuck+1] (single block)
// ---------------------------------------------------------------------------
__global__ void __launch_bounds__(256) kS2_scantotals(
    const int* __restrict__ BinTotal, int* __restrict__ BucketStart,
    int nbuck, int n_edges) {
    __shared__ int s[256];
    int t = threadIdx.x;
    int v[4];
#pragma unroll
    for (int j = 0; j < 4; ++j) {
        int idx = t * 4 + j;
        v[j] = (idx < nbuck) ? BinTotal[idx] : 0;
    }
    int tsum = v[0] + v[1] + v[2] + v[3];
    s[t] = tsum;
    __syncthreads();
    for (int off = 1; off < 256; off <<= 1) {
        int x = (t >= off) ? s[t - off] : 0;
        __syncthreads();
        s[t] += x;
        __syncthreads();
    }
    int run = s[t] - tsum;
#pragma unroll
    for (int j = 0; j < 4; ++j) {
        int idx = t * 4 + j;
        if (idx < nbuck) BucketStart[idx] = run;
        run += v[j];
    }
    if (t == 0) BucketStart[nbuck] = n_edges;
}

// ---------------------------------------------------------------------------
// kB: scatter edges to bucket regions, packed (row<<7)|(col&127); LDS cursors
// seeded from BucketStart + tickets (atomic-free at global scope).
// ---------------------------------------------------------------------------
__global__ void __launch_bounds__(256) kB_scatter(
    const int* __restrict__ row, const int* __restrict__ col,
    const int* __restrict__ BucketStart, const int* __restrict__ tickets,
    unsigned int* __restrict__ EdgeBuf, int n_edges, int nbuck, int chunk) {
    __shared__ int cur[MAXBUCK];
    const int* trow = tickets + (size_t)blockIdx.x * nbuck;
    int t = threadIdx.x;
    for (int i = t; i < nbuck; i += 256)
        cur[i] = BucketStart[i] + trow[i];
    __syncthreads();
    int start = blockIdx.x * chunk;
    int end = min(n_edges, start + chunk);
    for (int i = start + t; i < end; i += 256) {
        int c = col[i];
        int r = row[i];
        int bin = c >> NPB_LOG;
        int p = atomicAdd(&cur[bin], 1);
        EdgeBuf[p] = ((unsigned int)r << NPB_LOG) | (unsigned int)(c & (NPB - 1));
    }
}

// ---------------------------------------------------------------------------
// kD: per-bucket degree histogram -> dis = rsqrt(deg) (coalesced write)
// ---------------------------------------------------------------------------
__global__ void __launch_bounds__(256) kD_degree(
    const unsigned int* __restrict__ EdgeBuf, const int* __restrict__ BucketStart,
    float* __restrict__ dis, int n_nodes) {
    __shared__ int cnt[NPB];
    int t = threadIdx.x;
    if (t < NPB) cnt[t] = 0;
    __syncthreads();
    int es = BucketStart[blockIdx.x];
    int ee = BucketStart[blockIdx.x + 1];
    for (int i = es + t; i < ee; i += 256)
        atomicAdd(&cnt[EdgeBuf[i] & (NPB - 1)], 1);
    __syncthreads();
    int nb0 = blockIdx.x << NPB_LOG;
    if (t < NPB) {
        int node = nb0 + t;
        if (node < n_nodes) {
            int d = cnt[t];
            dis[node] = (d > 0) ? rsqrtf((float)d) : 0.0f;
        }
    }
}

// ---------------------------------------------------------------------------
// k_matmul_mfma: h(bf16) = (x @ W) * dis via f16 MFMA 16x16x32.
// One wave per 16-node tile; W fragments hoisted; no LDS/barriers.
// ---------------------------------------------------------------------------
__global__ void __launch_bounds__(256) k_matmul_mfma(
    const float* __restrict__ x, const float* __restrict__ W,
    const float* __restrict__ dis, unsigned short* __restrict__ h, int n_nodes) {
    const int lane = threadIdx.x & 63;
    const int m = lane & 15;       // A-row / D-col index
    const int q = lane >> 4;       // quad
    const int wid = (blockIdx.x * blockDim.x + threadIdx.x) >> 6;
    const int ntiles = (n_nodes + 15) >> 4;
    if (wid >= ntiles) return;

    half8 bfrag[4][4];
#pragma unroll
    for (int kt = 0; kt < 4; ++kt) {
#pragma unroll
        for (int nt = 0; nt < 4; ++nt) {
            int k0 = kt * 32 + q * 8;
            int c = nt * 16 + m;
#pragma unroll
            for (int j = 0; j < 8; ++j)
                bfrag[kt][nt][j] = (_Float16)W[(size_t)(k0 + j) * OUT_DIM + c];
        }
    }

    const int nb = wid << 4;
    int arow = nb + m;
    if (arow >= n_nodes) arow = n_nodes - 1;
    const float* xr = x + (size_t)arow * IN_DIM;

    f32x4 acc[4];
#pragma unroll
    for (int nt = 0; nt < 4; ++nt) acc[nt] = (f32x4){0.f, 0.f, 0.f, 0.f};

#pragma unroll
    for (int kt = 0; kt < 4; ++kt) {
        const float4* xp = (const float4*)(xr + kt * 32 + q * 8);
        float4 lo = xp[0];
        float4 hi = xp[1];
        half8 afrag;
        afrag[0] = (_Float16)lo.x; afrag[1] = (_Float16)lo.y;
        afrag[2] = (_Float16)lo.z; afrag[3] = (_Float16)lo.w;
        afrag[4] = (_Float16)hi.x; afrag[5] = (_Float16)hi.y;
        afrag[6] = (_Float16)hi.z; afrag[7] = (_Float16)hi.w;
#pragma unroll
        for (int nt = 0; nt < 4; ++nt)
            acc[nt] = __builtin_amdgcn_mfma_f32_16x16x32_f16(afrag, bfrag[kt][nt],
                                                             acc[nt], 0, 0, 0);
    }

#pragma unroll
    for (int r = 0; r < 4; ++r) {
        int node = nb + q * 4 + r;
        if (node < n_nodes) {
            float dv = dis[node];
            unsigned short* hp = h + (size_t)node * OUT_DIM + m;
#pragma unroll
            for (int nt = 0; nt < 4; ++nt)
                hp[nt * 16] = f2bf(acc[nt][r] * dv);
        }
    }
}

// ---------------------------------------------------------------------------
// kE: per-bucket aggregation with LDS fp32 accumulators (no sort needed).
// One block per 128-node bucket; acc[128][65] fp32 in LDS (stride-65 pads
// the power-of-2 bank pattern). Each quarter-wave gathers one edge's h-row
// (uint2 = 4 bf16 cols/lane), 8 waves x 2 edges = 16 edges in flight/block,
// ds_add_f32 accumulate. Epilogue: out = relu(dis[c]*acc + b), float4 stores.
// ---------------------------------------------------------------------------
__global__ void __launch_bounds__(512) kE_aggregate(
    const unsigned int* __restrict__ EdgeBuf, const int* __restrict__ BucketStart,
    const float* __restrict__ dis, const unsigned short* __restrict__ h,
    const float* __restrict__ b, float* __restrict__ out, int n_nodes) {
    __shared__ float accL[NPB * ACC_STRIDE];  // 33.3 KB
    int t = threadIdx.x;
    for (int i = t; i < NPB * ACC_STRIDE; i += 512) accL[i] = 0.0f;
    int es = BucketStart[blockIdx.x];
    int ee = BucketStart[blockIdx.x + 1];
    int nb0 = blockIdx.x << NPB_LOG;
    int nn = min(NPB, n_nodes - nb0);
    __syncthreads();

    const int lane = t & 63;
    const int wv = t >> 6;          // 0..7
    const int quarter = lane >> 4;  // 0..3
    const int qlane = lane & 15;    // covers 64 cols as 4 each

    for (int base = es + wv * 8; base < ee; base += 64) {  // 8 waves x 8 edges
        int iA = base + quarter;
        int iB = base + quarter + 4;
        unsigned int eA = EdgeBuf[iA < ee ? iA : es];
        unsigned int eB = EdgeBuf[iB < ee ? iB : es];
        int rA = (int)(eA >> NPB_LOG), cA = (int)(eA & (NPB - 1));
        int rB = (int)(eB >> NPB_LOG), cB = (int)(eB & (NPB - 1));
        uint2 vA = make_uint2(0u, 0u), vB = make_uint2(0u, 0u);
        if (iA < ee) vA = *(const uint2*)(h + (size_t)rA * OUT_DIM + qlane * 4);
        if (iB < ee) vB = *(const uint2*)(h + (size_t)rB * OUT_DIM + qlane * 4);
        if (iA < ee) {
            float* ap = accL + cA * ACC_STRIDE + qlane * 4;
            atomicAdd(ap + 0, __uint_as_float(vA.x << 16));
            atomicAdd(ap + 1, __uint_as_float(vA.x & 0xFFFF0000u));
            atomicAdd(ap + 2, __uint_as_float(vA.y << 16));
            atomicAdd(ap + 3, __uint_as_float(vA.y & 0xFFFF0000u));
        }
        if (iB < ee) {
            float* bp = accL + cB * ACC_STRIDE + qlane * 4;
            atomicAdd(bp + 0, __uint_as_float(vB.x << 16));
            atomicAdd(bp + 1, __uint_as_float(vB.x & 0xFFFF0000u));
            atomicAdd(bp + 2, __uint_as_float(vB.y << 16));
            atomicAdd(bp + 3, __uint_as_float(vB.y & 0xFFFF0000u));
        }
    }
    __syncthreads();

    // epilogue: 512 threads -> 32 nodes per pass (16 threads/node, float4 each)
    int q4 = (t & 15) * 4;
    for (int nl = (t >> 4); nl < nn; nl += 32) {
        float dv = dis[nb0 + nl];
        const float* ap = accL + nl * ACC_STRIDE + q4;
        float4 o;
        o.x = fmaxf(fmaf(ap[0], dv, b[q4 + 0]), 0.0f);
        o.y = fmaxf(fmaf(ap[1], dv, b[q4 + 1]), 0.0f);
        o.z = fmaxf(fmaf(ap[2], dv, b[q4 + 2]), 0.0f);
        o.w = fmaxf(fmaf(ap[3], dv, b[q4 + 3]), 0.0f);
        *(float4*)(out + (size_t)(nb0 + nl) * OUT_DIM + q4) = o;
    }
}

// ---------------------------------------------------------------------------
// Fallback path (exotic sizes / small workspace): atomic scatter, fp32 h
// ---------------------------------------------------------------------------
#define MM_NODES 16
__global__ void __launch_bounds__(256) k_matmul_f32(
    const float* __restrict__ x, const float* __restrict__ W,
    const float* __restrict__ dis, float* __restrict__ h, int n_nodes) {
    __shared__ float xs[MM_NODES * IN_DIM];
    const int lane = threadIdx.x & 63;
    const int wv = threadIdx.x >> 6;
    float w[IN_DIM];
#pragma unroll
    for (int k = 0; k < IN_DIM; ++k) w[k] = W[k * OUT_DIM + lane];
    int nchunks = (n_nodes + MM_NODES - 1) / MM_NODES;
    for (int ch = blockIdx.x; ch < nchunks; ch += gridDim.x) {
        int base = ch * MM_NODES;
        int nrows = min(MM_NODES, n_nodes - base);
        __syncthreads();
        const float4* xg = (const float4*)(x + (size_t)base * IN_DIM);
        int nf4 = nrows * IN_DIM / 4;
        for (int i = threadIdx.x; i < nf4; i += 256) ((float4*)xs)[i] = xg[i];
        __syncthreads();
#pragma unroll
        for (int j = 0; j < 4; ++j) {
            int local = wv * 4 + j;
            int node = base + local;
            if (local < nrows) {
                const float4* xr = (const float4*)(xs + local * IN_DIM);
                float acc = 0.0f;
#pragma unroll
                for (int k4 = 0; k4 < IN_DIM / 4; ++k4) {
                    float4 xv = xr[k4];
                    acc = fmaf(xv.x, w[k4 * 4 + 0], acc);
                    acc = fmaf(xv.y, w[k4 * 4 + 1], acc);
                    acc = fmaf(xv.z, w[k4 * 4 + 2], acc);
                    acc = fmaf(xv.w, w[k4 * 4 + 3], acc);
                }
                h[(size_t)node * OUT_DIM + lane] = acc * dis[node];
            }
        }
    }
}

__global__ void k_degree_fb(const int* __restrict__ col, int* __restrict__ deg,
                            int n_edges) {
    int i = blockIdx.x * blockDim.x + threadIdx.x;
    int stride = gridDim.x * blockDim.x;
    for (; i < n_edges; i += stride) atomicAdd(&deg[col[i]], 1);
}

__global__ void k_rsqrt_fb(const int* __restrict__ deg, float* __restrict__ dis, int n) {
    int i = blockIdx.x * blockDim.x + threadIdx.x;
    if (i < n) {
        int d = deg[i];
        dis[i] = (d > 0) ? rsqrtf((float)d) : 0.0f;
    }
}

__global__ void __launch_bounds__(256) k_scatter_fb(
    const int* __restrict__ row, const int* __restrict__ col,
    const float* __restrict__ dis, const float* __restrict__ h,
    float* __restrict__ out, int n_edges) {
    const int lane = threadIdx.x & 63;
    int e = (blockIdx.x * blockDim.x + threadIdx.x) >> 6;
    int nw = (gridDim.x * blockDim.x) >> 6;
    for (; e < n_edges; e += nw) {
        int r = row[e];
        int c = col[e];
        float v = h[(size_t)r * OUT_DIM + lane] * dis[c];
        atomicAdd(&out[(size_t)c * OUT_DIM + lane], v);
    }
}

__global__ void k_bias_relu_fb(float* __restrict__ out, const float* __restrict__ b,
                               int total) {
    int i = blockIdx.x * blockDim.x + threadIdx.x;
    int stride = gridDim.x * blockDim.x;
    for (; i < total; i += stride) {
        float v = out[i] + b[i & (OUT_DIM - 1)];
        out[i] = fmaxf(v, 0.0f);
    }
}

extern "C" void kernel_launch(void* const* d_in, const int* in_sizes, int n_in,
                              void* d_out, int out_size, void* d_ws, size_t ws_size,
                              hipStream_t stream) {
    const float* x = (const float*)d_in[0];
    const int* ei = (const int*)d_in[1];  // [2, E] int32
    const float* W = (const float*)d_in[2];
    const float* b = (const float*)d_in[3];
    float* out = (float*)d_out;

    const int n_nodes = in_sizes[0] / IN_DIM;
    const int n_edges = in_sizes[1] / 2;
    const int* row = ei;
    const int* col = ei + n_edges;

    const int nbuck = (n_nodes + NPB - 1) >> NPB_LOG;
    const int chunk = (n_edges + B1 - 1) / B1;

    // ---- workspace layout ----
    char* wsb = (char*)d_ws;
    size_t off = 0;
    int* BinTotal = (int*)(wsb + off);   off += align_up((size_t)nbuck * 4, 256);
    int* BucketStart = (int*)(wsb + off);off += align_up((size_t)(nbuck + 1) * 4, 256);
    int* tickets = (int*)(wsb + off);    off += align_up((size_t)B1 * nbuck * 4, 256);
    float* dis = (float*)(wsb + off);    off += align_up((size_t)n_nodes * 4, 256);
    unsigned int* EdgeBuf = (unsigned int*)(wsb + off);
                                         off += align_up((size_t)n_edges * 4, 256);
    unsigned short* h = (unsigned short*)(wsb + off);
                                         off += (size_t)n_nodes * OUT_DIM * 2;
    const size_t needed = off;

    const bool ok = (ws_size >= needed) && (nbuck <= MAXBUCK) &&
                    (n_nodes <= (NPB * MAXBUCK)) && (n_nodes <= (1 << 23));

    if (ok) {
        hipMemsetAsync(BinTotal, 0, (size_t)nbuck * 4, stream);
        kA_ticket<<<B1, 256, 0, stream>>>(col, BinTotal, tickets, n_edges, nbuck,
                                          chunk);
        kS2_scantotals<<<1, 256, 0, stream>>>(BinTotal, BucketStart, nbuck, n_edges);
        kB_scatter<<<B1, 256, 0, stream>>>(row, col, BucketStart, tickets, EdgeBuf,
                                           n_edges, nbuck, chunk);
        kD_degree<<<nbuck, 256, 0, stream>>>(EdgeBuf, BucketStart, dis, n_nodes);
        int ntiles = (n_nodes + 15) / 16;           // one wave per 16 nodes
        int mm_blocks = (ntiles + 3) / 4;           // 4 waves per block
        k_matmul_mfma<<<mm_blocks, 256, 0, stream>>>(x, W, dis, h, n_nodes);
        kE_aggregate<<<nbuck, 512, 0, stream>>>(EdgeBuf, BucketStart, dis, h, b,
                                                out, n_nodes);
    } else {
        // ---- fallback: atomic scatter, fp32 h ----
        char* p = (char*)d_ws;
        int* deg_f = (int*)p;
        float* dis_f = (float*)(p + align_up((size_t)n_nodes * 4, 256));
        float* h_f = (float*)(p + 2 * align_up((size_t)n_nodes * 4, 256));
        hipMemsetAsync(deg_f, 0, (size_t)n_nodes * 4, stream);
        hipMemsetAsync(out, 0, (size_t)out_size * 4, stream);
        k_degree_fb<<<1024, 256, 0, stream>>>(col, deg_f, n_edges);
        k_rsqrt_fb<<<(n_nodes + 255) / 256, 256, 0, stream>>>(deg_f, dis_f, n_nodes);
        k_matmul_f32<<<1024, 256, 0, stream>>>(x, W, dis_f, h_f, n_nodes);
        k_scatter_fb<<<2048, 256, 0, stream>>>(row, col, dis_f, h_f, out, n_edges);
        k_bias_relu_fb<<<2048, 256, 0, stream>>>(out, b, n_nodes * OUT_DIM);
    }
}

// Round 10
// 198.165 us; speedup vs baseline: 4.1781x; 4.1781x over previous
//
#include <hip/hip_runtime.h>
#include <hip/hip_bf16.h>

#define IN_DIM 128
#define OUT_DIM 64
#define NPB_LOG 7                  // 128 nodes per bucket
#define NPB (1 << NPB_LOG)
#define MAXBUCK 1024               // supports n_nodes <= 128K
#define B1 512                     // bucketing blocks (kA/kB); must match
#define CAP 4096                   // LDS sorted-edge capacity per bucket (16 KB)

static inline size_t align_up(size_t v, size_t a) { return (v + a - 1) & ~(a - 1); }

__device__ __forceinline__ unsigned short f2bf(float f) {
    unsigned int x = __float_as_uint(f);
    unsigned int r = (x + 0x7fffu + ((x >> 16) & 1u)) >> 16;  // RTNE
    return (unsigned short)r;
}

typedef _Float16 half8 __attribute__((ext_vector_type(8)));
typedef float f32x4 __attribute__((ext_vector_type(4)));

// ---------------------------------------------------------------------------
// kA_ticket: per-block LDS histogram of col>>7 + global ticket atomics.
// tickets[blk][bin] = block's exclusive base within bin; BinTotal accumulates.
// ---------------------------------------------------------------------------
__global__ void __launch_bounds__(256) kA_ticket(
    const int* __restrict__ col, int* __restrict__ BinTotal,
    int* __restrict__ tickets, int n_edges, int nbuck, int chunk) {
    __shared__ int hist[MAXBUCK];
    int t = threadIdx.x;
    for (int i = t; i < nbuck; i += 256) hist[i] = 0;
    __syncthreads();
    int start = blockIdx.x * chunk;
    int end = min(n_edges, start + chunk);
    for (int i = start + t; i < end; i += 256)
        atomicAdd(&hist[col[i] >> NPB_LOG], 1);
    __syncthreads();
    int* trow = tickets + (size_t)blockIdx.x * nbuck;
    for (int i = t; i < nbuck; i += 256)
        trow[i] = atomicAdd(&BinTotal[i], hist[i]);
}

// ---------------------------------------------------------------------------
// kS2: exclusive scan of BinTotal -> BucketStart[nbuck+1] (single block)
// ---------------------------------------------------------------------------
__global__ void __launch_bounds__(256) kS2_scantotals(
    const int* __restrict__ BinTotal, int* __restrict__ BucketStart,
    int nbuck, int n_edges) {
    __shared__ int s[256];
    int t = threadIdx.x;
    int v[4];
#pragma unroll
    for (int j = 0; j < 4; ++j) {
        int idx = t * 4 + j;
        v[j] = (idx < nbuck) ? BinTotal[idx] : 0;
    }
    int tsum = v[0] + v[1] + v[2] + v[3];
    s[t] = tsum;
    __syncthreads();
    for (int off = 1; off < 256; off <<= 1) {
        int x = (t >= off) ? s[t - off] : 0;
        __syncthreads();
        s[t] += x;
        __syncthreads();
    }
    int run = s[t] - tsum;
#pragma unroll
    for (int j = 0; j < 4; ++j) {
        int idx = t * 4 + j;
        if (idx < nbuck) BucketStart[idx] = run;
        run += v[j];
    }
    if (t == 0) BucketStart[nbuck] = n_edges;
}

// ---------------------------------------------------------------------------
// kB: scatter edges to bucket regions, packed (row<<7)|(col&127); LDS cursors
// seeded from BucketStart + tickets.
// ---------------------------------------------------------------------------
__global__ void __launch_bounds__(256) kB_scatter(
    const int* __restrict__ row, const int* __restrict__ col,
    const int* __restrict__ BucketStart, const int* __restrict__ tickets,
    unsigned int* __restrict__ EdgeBuf, int n_edges, int nbuck, int chunk) {
    __shared__ int cur[MAXBUCK];
    const int* trow = tickets + (size_t)blockIdx.x * nbuck;
    int t = threadIdx.x;
    for (int i = t; i < nbuck; i += 256)
        cur[i] = BucketStart[i] + trow[i];
    __syncthreads();
    int start = blockIdx.x * chunk;
    int end = min(n_edges, start + chunk);
    for (int i = start + t; i < end; i += 256) {
        int c = col[i];
        int r = row[i];
        int bin = c >> NPB_LOG;
        int p = atomicAdd(&cur[bin], 1);
        EdgeBuf[p] = ((unsigned int)r << NPB_LOG) | (unsigned int)(c & (NPB - 1));
    }
}

// ---------------------------------------------------------------------------
// kD: per-bucket degree histogram -> dis = rsqrt(deg) (coalesced write).
// Must run before matmul (h is pre-scaled by dis[row]).
// ---------------------------------------------------------------------------
__global__ void __launch_bounds__(256) kD_degree(
    const unsigned int* __restrict__ EdgeBuf, const int* __restrict__ BucketStart,
    float* __restrict__ dis, int n_nodes) {
    __shared__ int cnt[NPB];
    int t = threadIdx.x;
    if (t < NPB) cnt[t] = 0;
    __syncthreads();
    int es = BucketStart[blockIdx.x];
    int ee = BucketStart[blockIdx.x + 1];
    for (int i = es + t; i < ee; i += 256)
        atomicAdd(&cnt[EdgeBuf[i] & (NPB - 1)], 1);
    __syncthreads();
    int nb0 = blockIdx.x << NPB_LOG;
    if (t < NPB) {
        int node = nb0 + t;
        if (node < n_nodes) {
            int d = cnt[t];
            dis[node] = (d > 0) ? rsqrtf((float)d) : 0.0f;
        }
    }
}

// ---------------------------------------------------------------------------
// k_matmul_mfma: h(bf16) = (x @ W) * dis via f16 MFMA 16x16x32.
// One wave per 16-node tile; W fragments hoisted; no LDS/barriers.
// ---------------------------------------------------------------------------
__global__ void __launch_bounds__(256) k_matmul_mfma(
    const float* __restrict__ x, const float* __restrict__ W,
    const float* __restrict__ dis, unsigned short* __restrict__ h, int n_nodes) {
    const int lane = threadIdx.x & 63;
    const int m = lane & 15;
    const int q = lane >> 4;
    const int wid = (blockIdx.x * blockDim.x + threadIdx.x) >> 6;
    const int ntiles = (n_nodes + 15) >> 4;
    if (wid >= ntiles) return;

    half8 bfrag[4][4];
#pragma unroll
    for (int kt = 0; kt < 4; ++kt) {
#pragma unroll
        for (int nt = 0; nt < 4; ++nt) {
            int k0 = kt * 32 + q * 8;
            int c = nt * 16 + m;
#pragma unroll
            for (int j = 0; j < 8; ++j)
                bfrag[kt][nt][j] = (_Float16)W[(size_t)(k0 + j) * OUT_DIM + c];
        }
    }

    const int nb = wid << 4;
    int arow = nb + m;
    if (arow >= n_nodes) arow = n_nodes - 1;
    const float* xr = x + (size_t)arow * IN_DIM;

    f32x4 acc[4];
#pragma unroll
    for (int nt = 0; nt < 4; ++nt) acc[nt] = (f32x4){0.f, 0.f, 0.f, 0.f};

#pragma unroll
    for (int kt = 0; kt < 4; ++kt) {
        const float4* xp = (const float4*)(xr + kt * 32 + q * 8);
        float4 lo = xp[0];
        float4 hi = xp[1];
        half8 afrag;
        afrag[0] = (_Float16)lo.x; afrag[1] = (_Float16)lo.y;
        afrag[2] = (_Float16)lo.z; afrag[3] = (_Float16)lo.w;
        afrag[4] = (_Float16)hi.x; afrag[5] = (_Float16)hi.y;
        afrag[6] = (_Float16)hi.z; afrag[7] = (_Float16)hi.w;
#pragma unroll
        for (int nt = 0; nt < 4; ++nt)
            acc[nt] = __builtin_amdgcn_mfma_f32_16x16x32_f16(afrag, bfrag[kt][nt],
                                                             acc[nt], 0, 0, 0);
    }

#pragma unroll
    for (int r = 0; r < 4; ++r) {
        int node = nb + q * 4 + r;
        if (node < n_nodes) {
            float dv = dis[node];
            unsigned short* hp = h + (size_t)node * OUT_DIM + m;
#pragma unroll
            for (int nt = 0; nt < 4; ++nt)
                hp[nt * 16] = f2bf(acc[nt][r] * dv);
        }
    }
}

// ---------------------------------------------------------------------------
// kF: fused per-bucket local sort (into LDS) + gather-aggregate.
// One block per 128-node bucket. Histogram -> scan -> place sorted row-ids in
// LDS sbuf -> per-node quarter-wave uint2 h-gather (round-8 proven pattern,
// adjacency via LDS broadcast reads). Int LDS atomics only (no fp32 LDS
// atomics -- round 9's 15x regression). Global spill path if bucket > CAP.
// ---------------------------------------------------------------------------
__global__ void __launch_bounds__(512) kF_sortagg(
    const unsigned int* __restrict__ EdgeBuf, const int* __restrict__ BucketStart,
    const float* __restrict__ dis, const unsigned short* __restrict__ h,
    const float* __restrict__ b, float* __restrict__ out,
    int* __restrict__ edge_src, int n_nodes) {
    __shared__ int cnt[NPB];
    __shared__ int seg[NPB];     // inclusive scan
    __shared__ int cursor[NPB];
    __shared__ int sbuf[CAP];
    int t = threadIdx.x;
    int es = BucketStart[blockIdx.x];
    int ee = BucketStart[blockIdx.x + 1];
    int ne = ee - es;
    int nb0 = blockIdx.x << NPB_LOG;

    if (t < NPB) cnt[t] = 0;
    __syncthreads();
    for (int i = es + t; i < ee; i += 512)
        atomicAdd(&cnt[EdgeBuf[i] & (NPB - 1)], 1);
    __syncthreads();

    // inclusive scan of cnt into seg (threads 0..127 participate)
    if (t < NPB) seg[t] = cnt[t];
    __syncthreads();
    for (int off = 1; off < NPB; off <<= 1) {
        int x = 0;
        if (t < NPB && t >= off) x = seg[t - off];
        __syncthreads();
        if (t < NPB) seg[t] += x;
        __syncthreads();
    }
    if (t < NPB) cursor[t] = seg[t] - cnt[t];  // exclusive start
    __syncthreads();

    const int lane = t & 63;
    const int wv = t >> 6;          // 0..7
    const int quarter = lane >> 4;  // 0..3
    const int qlane = lane & 15;
    float4 bias = ((const float4*)b)[qlane];

    if (ne <= CAP) {
        // ---- place sorted row-ids into LDS (second EdgeBuf read is L2-hot) ----
        for (int i = es + t; i < ee; i += 512) {
            unsigned int v = EdgeBuf[i];
            int c = (int)(v & (NPB - 1));
            int p = atomicAdd(&cursor[c], 1);
            sbuf[p] = (int)(v >> NPB_LOG);
        }
        __syncthreads();

        // ---- aggregate: wave per node, quarter-wave edge parallelism ----
        for (int nl = wv; nl < NPB; nl += 8) {
            int node = nb0 + nl;
            if (node >= n_nodes) break;
            int e_ = seg[nl];
            int s_ = e_ - cnt[nl];
            float a0 = 0.f, a1 = 0.f, a2 = 0.f, a3 = 0.f;
            for (int j0 = s_; j0 < e_; j0 += 8) {
                int iA = j0 + quarter;
                int iB = j0 + quarter + 4;
                int rA = sbuf[iA < e_ ? iA : s_];   // LDS broadcast read
                int rB = sbuf[iB < e_ ? iB : s_];
                uint2 vA = make_uint2(0u, 0u), vB = make_uint2(0u, 0u);
                if (iA < e_)
                    vA = *(const uint2*)(h + (size_t)rA * OUT_DIM + qlane * 4);
                if (iB < e_)
                    vB = *(const uint2*)(h + (size_t)rB * OUT_DIM + qlane * 4);
                a0 += __uint_as_float(vA.x << 16);
                a1 += __uint_as_float(vA.x & 0xFFFF0000u);
                a2 += __uint_as_float(vA.y << 16);
                a3 += __uint_as_float(vA.y & 0xFFFF0000u);
                a0 += __uint_as_float(vB.x << 16);
                a1 += __uint_as_float(vB.x & 0xFFFF0000u);
                a2 += __uint_as_float(vB.y << 16);
                a3 += __uint_as_float(vB.y & 0xFFFF0000u);
            }
            a0 += __shfl_xor(a0, 16, 64); a0 += __shfl_xor(a0, 32, 64);
            a1 += __shfl_xor(a1, 16, 64); a1 += __shfl_xor(a1, 32, 64);
            a2 += __shfl_xor(a2, 16, 64); a2 += __shfl_xor(a2, 32, 64);
            a3 += __shfl_xor(a3, 16, 64); a3 += __shfl_xor(a3, 32, 64);
            if (quarter == 0) {
                float dv = dis[node];
                float4 o;
                o.x = fmaxf(fmaf(a0, dv, bias.x), 0.f);
                o.y = fmaxf(fmaf(a1, dv, bias.y), 0.f);
                o.z = fmaxf(fmaf(a2, dv, bias.z), 0.f);
                o.w = fmaxf(fmaf(a3, dv, bias.w), 0.f);
                ((float4*)(out + (size_t)node * OUT_DIM))[qlane] = o;
            }
        }
    } else {
        // ---- spill path (bucket too big for LDS): sort into global region ----
        for (int i = es + t; i < ee; i += 512) {
            unsigned int v = EdgeBuf[i];
            int c = (int)(v & (NPB - 1));
            int p = atomicAdd(&cursor[c], 1);
            edge_src[es + p] = (int)(v >> NPB_LOG);
        }
        __threadfence();
        __syncthreads();
        for (int nl = wv; nl < NPB; nl += 8) {
            int node = nb0 + nl;
            if (node >= n_nodes) break;
            int e_ = seg[nl];
            int s_ = e_ - cnt[nl];
            float a0 = 0.f, a1 = 0.f, a2 = 0.f, a3 = 0.f;
            for (int j0 = s_; j0 < e_; j0 += 8) {
                int iA = j0 + quarter;
                int iB = j0 + quarter + 4;
                int rA = edge_src[es + (iA < e_ ? iA : s_)];
                int rB = edge_src[es + (iB < e_ ? iB : s_)];
                uint2 vA = make_uint2(0u, 0u), vB = make_uint2(0u, 0u);
                if (iA < e_)
                    vA = *(const uint2*)(h + (size_t)rA * OUT_DIM + qlane * 4);
                if (iB < e_)
                    vB = *(const uint2*)(h + (size_t)rB * OUT_DIM + qlane * 4);
                a0 += __uint_as_float(vA.x << 16);
                a1 += __uint_as_float(vA.x & 0xFFFF0000u);
                a2 += __uint_as_float(vA.y << 16);
                a3 += __uint_as_float(vA.y & 0xFFFF0000u);
                a0 += __uint_as_float(vB.x << 16);
                a1 += __uint_as_float(vB.x & 0xFFFF0000u);
                a2 += __uint_as_float(vB.y << 16);
                a3 += __uint_as_float(vB.y & 0xFFFF0000u);
            }
            a0 += __shfl_xor(a0, 16, 64); a0 += __shfl_xor(a0, 32, 64);
            a1 += __shfl_xor(a1, 16, 64); a1 += __shfl_xor(a1, 32, 64);
            a2 += __shfl_xor(a2, 16, 64); a2 += __shfl_xor(a2, 32, 64);
            a3 += __shfl_xor(a3, 16, 64); a3 += __shfl_xor(a3, 32, 64);
            if (quarter == 0) {
                float dv = dis[node];
                float4 o;
                o.x = fmaxf(fmaf(a0, dv, bias.x), 0.f);
                o.y = fmaxf(fmaf(a1, dv, bias.y), 0.f);
                o.z = fmaxf(fmaf(a2, dv, bias.z), 0.f);
                o.w = fmaxf(fmaf(a3, dv, bias.w), 0.f);
                ((float4*)(out + (size_t)node * OUT_DIM))[qlane] = o;
            }
        }
    }
}

// ---------------------------------------------------------------------------
// Fallback path (exotic sizes / small workspace): atomic scatter, fp32 h
// ---------------------------------------------------------------------------
#define MM_NODES 16
__global__ void __launch_bounds__(256) k_matmul_f32(
    const float* __restrict__ x, const float* __restrict__ W,
    const float* __restrict__ dis, float* __restrict__ h, int n_nodes) {
    __shared__ float xs[MM_NODES * IN_DIM];
    const int lane = threadIdx.x & 63;
    const int wv = threadIdx.x >> 6;
    float w[IN_DIM];
#pragma unroll
    for (int k = 0; k < IN_DIM; ++k) w[k] = W[k * OUT_DIM + lane];
    int nchunks = (n_nodes + MM_NODES - 1) / MM_NODES;
    for (int ch = blockIdx.x; ch < nchunks; ch += gridDim.x) {
        int base = ch * MM_NODES;
        int nrows = min(MM_NODES, n_nodes - base);
        __syncthreads();
        const float4* xg = (const float4*)(x + (size_t)base * IN_DIM);
        int nf4 = nrows * IN_DIM / 4;
        for (int i = threadIdx.x; i < nf4; i += 256) ((float4*)xs)[i] = xg[i];
        __syncthreads();
#pragma unroll
        for (int j = 0; j < 4; ++j) {
            int local = wv * 4 + j;
            int node = base + local;
            if (local < nrows) {
                const float4* xr = (const float4*)(xs + local * IN_DIM);
                float acc = 0.0f;
#pragma unroll
                for (int k4 = 0; k4 < IN_DIM / 4; ++k4) {
                    float4 xv = xr[k4];
                    acc = fmaf(xv.x, w[k4 * 4 + 0], acc);
                    acc = fmaf(xv.y, w[k4 * 4 + 1], acc);
                    acc = fmaf(xv.z, w[k4 * 4 + 2], acc);
                    acc = fmaf(xv.w, w[k4 * 4 + 3], acc);
                }
                h[(size_t)node * OUT_DIM + lane] = acc * dis[node];
            }
        }
    }
}

__global__ void k_degree_fb(const int* __restrict__ col, int* __restrict__ deg,
                            int n_edges) {
    int i = blockIdx.x * blockDim.x + threadIdx.x;
    int stride = gridDim.x * blockDim.x;
    for (; i < n_edges; i += stride) atomicAdd(&deg[col[i]], 1);
}

__global__ void k_rsqrt_fb(const int* __restrict__ deg, float* __restrict__ dis, int n) {
    int i = blockIdx.x * blockDim.x + threadIdx.x;
    if (i < n) {
        int d = deg[i];
        dis[i] = (d > 0) ? rsqrtf((float)d) : 0.0f;
    }
}

__global__ void __launch_bounds__(256) k_scatter_fb(
    const int* __restrict__ row, const int* __restrict__ col,
    const float* __restrict__ dis, const float* __restrict__ h,
    float* __restrict__ out, int n_edges) {
    const int lane = threadIdx.x & 63;
    int e = (blockIdx.x * blockDim.x + threadIdx.x) >> 6;
    int nw = (gridDim.x * blockDim.x) >> 6;
    for (; e < n_edges; e += nw) {
        int r = row[e];
        int c = col[e];
        float v = h[(size_t)r * OUT_DIM + lane] * dis[c];
        atomicAdd(&out[(size_t)c * OUT_DIM + lane], v);
    }
}

__global__ void k_bias_relu_fb(float* __restrict__ out, const float* __restrict__ b,
                               int total) {
    int i = blockIdx.x * blockDim.x + threadIdx.x;
    int stride = gridDim.x * blockDim.x;
    for (; i < total; i += stride) {
        float v = out[i] + b[i & (OUT_DIM - 1)];
        out[i] = fmaxf(v, 0.0f);
    }
}

extern "C" void kernel_launch(void* const* d_in, const int* in_sizes, int n_in,
                              void* d_out, int out_size, void* d_ws, size_t ws_size,
                              hipStream_t stream) {
    const float* x = (const float*)d_in[0];
    const int* ei = (const int*)d_in[1];  // [2, E] int32
    const float* W = (const float*)d_in[2];
    const float* b = (const float*)d_in[3];
    float* out = (float*)d_out;

    const int n_nodes = in_sizes[0] / IN_DIM;
    const int n_edges = in_sizes[1] / 2;
    const int* row = ei;
    const int* col = ei + n_edges;

    const int nbuck = (n_nodes + NPB - 1) >> NPB_LOG;
    const int chunk = (n_edges + B1 - 1) / B1;

    // ---- workspace layout ----
    char* wsb = (char*)d_ws;
    size_t off = 0;
    int* BinTotal = (int*)(wsb + off);   off += align_up((size_t)nbuck * 4, 256);
    int* BucketStart = (int*)(wsb + off);off += align_up((size_t)(nbuck + 1) * 4, 256);
    int* tickets = (int*)(wsb + off);    off += align_up((size_t)B1 * nbuck * 4, 256);
    float* dis = (float*)(wsb + off);    off += align_up((size_t)n_nodes * 4, 256);
    unsigned int* EdgeBuf = (unsigned int*)(wsb + off);
                                         off += align_up((size_t)n_edges * 4, 256);
    int* edge_src = (int*)(wsb + off);   off += align_up((size_t)n_edges * 4, 256);
    unsigned short* h = (unsigned short*)(wsb + off);
                                         off += (size_t)n_nodes * OUT_DIM * 2;
    const size_t needed = off;

    const bool ok = (ws_size >= needed) && (nbuck <= MAXBUCK) &&
                    (n_nodes <= (1 << 24));

    if (ok) {
        hipMemsetAsync(BinTotal, 0, (size_t)nbuck * 4, stream);
        kA_ticket<<<B1, 256, 0, stream>>>(col, BinTotal, tickets, n_edges, nbuck,
                                          chunk);
        kS2_scantotals<<<1, 256, 0, stream>>>(BinTotal, BucketStart, nbuck, n_edges);
        kB_scatter<<<B1, 256, 0, stream>>>(row, col, BucketStart, tickets, EdgeBuf,
                                           n_edges, nbuck, chunk);
        kD_degree<<<nbuck, 256, 0, stream>>>(EdgeBuf, BucketStart, dis, n_nodes);
        int ntiles = (n_nodes + 15) / 16;
        int mm_blocks = (ntiles + 3) / 4;
        k_matmul_mfma<<<mm_blocks, 256, 0, stream>>>(x, W, dis, h, n_nodes);
        kF_sortagg<<<nbuck, 512, 0, stream>>>(EdgeBuf, BucketStart, dis, h, b,
                                              out, edge_src, n_nodes);
    } else {
        // ---- fallback: atomic scatter, fp32 h ----
        char* p = (char*)d_ws;
        int* deg_f = (int*)p;
        float* dis_f = (float*)(p + align_up((size_t)n_nodes * 4, 256));
        float* h_f = (float*)(p + 2 * align_up((size_t)n_nodes * 4, 256));
        hipMemsetAsync(deg_f, 0, (size_t)n_nodes * 4, stream);
        hipMemsetAsync(out, 0, (size_t)out_size * 4, stream);
        k_degree_fb<<<1024, 256, 0, stream>>>(col, deg_f, n_edges);
        k_rsqrt_fb<<<(n_nodes + 255) / 256, 256, 0, stream>>>(deg_f, dis_f, n_nodes);
        k_matmul_f32<<<1024, 256, 0, stream>>>(x, W, dis_f, h_f, n_nodes);
        k_scatter_fb<<<2048, 256, 0, stream>>>(row, col, dis_f, h_f, out, n_edges);
        k_bias_relu_fb<<<2048, 256, 0, stream>>>(out, b, n_nodes * OUT_DIM);
    }
}

// Round 11
// 193.264 us; speedup vs baseline: 4.2841x; 1.0254x over previous
//
#include <hip/hip_runtime.h>
#include <hip/hip_bf16.h>

#define IN_DIM 128
#define OUT_DIM 64
#define CLOG 9                     // coarse bucket: 512 nodes (scatter granularity)
#define CNPB (1 << CLOG)
#define FLOG 7                     // fine bucket: 128 nodes (aggregate granularity)
#define FNPB (1 << FLOG)
#define MAXCOARSE 1024             // supports n_nodes <= 512K
#define B1 256                     // bucketing blocks; 32-edge runs per (blk,bin)
#define CAP 4096                   // LDS sorted-edge capacity per fine bucket

static inline size_t align_up(size_t v, size_t a) { return (v + a - 1) & ~(a - 1); }

__device__ __forceinline__ unsigned short f2bf(float f) {
    unsigned int x = __float_as_uint(f);
    unsigned int r = (x + 0x7fffu + ((x >> 16) & 1u)) >> 16;  // RTNE
    return (unsigned short)r;
}

typedef _Float16 half8 __attribute__((ext_vector_type(8)));
typedef float f32x4 __attribute__((ext_vector_type(4)));

// ---------------------------------------------------------------------------
// kA_ticket: per-block LDS histogram of col>>9 + global ticket atomics.
// tickets[blk][bin] = block's exclusive base within bin; BinTotal accumulates.
// ---------------------------------------------------------------------------
__global__ void __launch_bounds__(256) kA_ticket(
    const int* __restrict__ col, int* __restrict__ BinTotal,
    int* __restrict__ tickets, int n_edges, int nbuck, int chunk) {
    __shared__ int hist[MAXCOARSE];
    int t = threadIdx.x;
    for (int i = t; i < nbuck; i += 256) hist[i] = 0;
    __syncthreads();
    int start = blockIdx.x * chunk;
    int end = min(n_edges, start + chunk);
    for (int i = start + t; i < end; i += 256)
        atomicAdd(&hist[col[i] >> CLOG], 1);
    __syncthreads();
    int* trow = tickets + (size_t)blockIdx.x * nbuck;
    for (int i = t; i < nbuck; i += 256)
        trow[i] = atomicAdd(&BinTotal[i], hist[i]);
}

// ---------------------------------------------------------------------------
// kS2: exclusive scan of BinTotal -> BucketStart[nbuck+1] (single block)
// ---------------------------------------------------------------------------
__global__ void __launch_bounds__(256) kS2_scantotals(
    const int* __restrict__ BinTotal, int* __restrict__ BucketStart,
    int nbuck, int n_edges) {
    __shared__ int s[256];
    int t = threadIdx.x;
    int v[4];
#pragma unroll
    for (int j = 0; j < 4; ++j) {
        int idx = t * 4 + j;
        v[j] = (idx < nbuck) ? BinTotal[idx] : 0;
    }
    int tsum = v[0] + v[1] + v[2] + v[3];
    s[t] = tsum;
    __syncthreads();
    for (int off = 1; off < 256; off <<= 1) {
        int x = (t >= off) ? s[t - off] : 0;
        __syncthreads();
        s[t] += x;
        __syncthreads();
    }
    int run = s[t] - tsum;
#pragma unroll
    for (int j = 0; j < 4; ++j) {
        int idx = t * 4 + j;
        if (idx < nbuck) BucketStart[idx] = run;
        run += v[j];
    }
    if (t == 0) BucketStart[nbuck] = n_edges;
}

// ---------------------------------------------------------------------------
// kB: scatter edges to coarse bucket regions, packed (row<<9)|(col&511).
// LDS cursors seeded from BucketStart + tickets. With B1=256 each (blk,bin)
// run is ~32 edges = 128 B, so L2 merges the stores into full lines.
// ---------------------------------------------------------------------------
__global__ void __launch_bounds__(256) kB_scatter(
    const int* __restrict__ row, const int* __restrict__ col,
    const int* __restrict__ BucketStart, const int* __restrict__ tickets,
    unsigned int* __restrict__ EdgeBuf, int n_edges, int nbuck, int chunk) {
    __shared__ int cur[MAXCOARSE];
    const int* trow = tickets + (size_t)blockIdx.x * nbuck;
    int t = threadIdx.x;
    for (int i = t; i < nbuck; i += 256)
        cur[i] = BucketStart[i] + trow[i];
    __syncthreads();
    int start = blockIdx.x * chunk;
    int end = min(n_edges, start + chunk);
    for (int i = start + t; i < end; i += 256) {
        int c = col[i];
        int r = row[i];
        int bin = c >> CLOG;
        int p = atomicAdd(&cur[bin], 1);
        EdgeBuf[p] = ((unsigned int)r << CLOG) | (unsigned int)(c & (CNPB - 1));
    }
}

// ---------------------------------------------------------------------------
// kD: per-coarse-bucket degree histogram -> dis = rsqrt(deg) (coalesced).
// Must run before matmul (h is pre-scaled by dis[row]).
// ---------------------------------------------------------------------------
__global__ void __launch_bounds__(256) kD_degree(
    const unsigned int* __restrict__ EdgeBuf, const int* __restrict__ BucketStart,
    float* __restrict__ dis, int n_nodes) {
    __shared__ int cnt[CNPB];
    int t = threadIdx.x;
    for (int i = t; i < CNPB; i += 256) cnt[i] = 0;
    __syncthreads();
    int es = BucketStart[blockIdx.x];
    int ee = BucketStart[blockIdx.x + 1];
    for (int i = es + t; i < ee; i += 256)
        atomicAdd(&cnt[EdgeBuf[i] & (CNPB - 1)], 1);
    __syncthreads();
    int nb0 = blockIdx.x << CLOG;
    for (int i = t; i < CNPB; i += 256) {
        int node = nb0 + i;
        if (node < n_nodes) {
            int d = cnt[i];
            dis[node] = (d > 0) ? rsqrtf((float)d) : 0.0f;
        }
    }
}

// ---------------------------------------------------------------------------
// k_matmul_mfma: h(bf16) = (x @ W) * dis via f16 MFMA 16x16x32.
// One wave per 16-node tile; W fragments hoisted; no LDS/barriers.
// ---------------------------------------------------------------------------
__global__ void __launch_bounds__(256) k_matmul_mfma(
    const float* __restrict__ x, const float* __restrict__ W,
    const float* __restrict__ dis, unsigned short* __restrict__ h, int n_nodes) {
    const int lane = threadIdx.x & 63;
    const int m = lane & 15;
    const int q = lane >> 4;
    const int wid = (blockIdx.x * blockDim.x + threadIdx.x) >> 6;
    const int ntiles = (n_nodes + 15) >> 4;
    if (wid >= ntiles) return;

    half8 bfrag[4][4];
#pragma unroll
    for (int kt = 0; kt < 4; ++kt) {
#pragma unroll
        for (int nt = 0; nt < 4; ++nt) {
            int k0 = kt * 32 + q * 8;
            int c = nt * 16 + m;
#pragma unroll
            for (int j = 0; j < 8; ++j)
                bfrag[kt][nt][j] = (_Float16)W[(size_t)(k0 + j) * OUT_DIM + c];
        }
    }

    const int nb = wid << 4;
    int arow = nb + m;
    if (arow >= n_nodes) arow = n_nodes - 1;
    const float* xr = x + (size_t)arow * IN_DIM;

    f32x4 acc[4];
#pragma unroll
    for (int nt = 0; nt < 4; ++nt) acc[nt] = (f32x4){0.f, 0.f, 0.f, 0.f};

#pragma unroll
    for (int kt = 0; kt < 4; ++kt) {
        const float4* xp = (const float4*)(xr + kt * 32 + q * 8);
        float4 lo = xp[0];
        float4 hi = xp[1];
        half8 afrag;
        afrag[0] = (_Float16)lo.x; afrag[1] = (_Float16)lo.y;
        afrag[2] = (_Float16)lo.z; afrag[3] = (_Float16)lo.w;
        afrag[4] = (_Float16)hi.x; afrag[5] = (_Float16)hi.y;
        afrag[6] = (_Float16)hi.z; afrag[7] = (_Float16)hi.w;
#pragma unroll
        for (int nt = 0; nt < 4; ++nt)
            acc[nt] = __builtin_amdgcn_mfma_f32_16x16x32_f16(afrag, bfrag[kt][nt],
                                                             acc[nt], 0, 0, 0);
    }

#pragma unroll
    for (int r = 0; r < 4; ++r) {
        int node = nb + q * 4 + r;
        if (node < n_nodes) {
            float dv = dis[node];
            unsigned short* hp = h + (size_t)node * OUT_DIM + m;
#pragma unroll
            for (int nt = 0; nt < 4; ++nt)
                hp[nt * 16] = f2bf(acc[nt][r] * dv);
        }
    }
}

// ---------------------------------------------------------------------------
// kF: fused fine-bucket local sort (into LDS) + gather-aggregate.
// Grid = ceil(n_nodes/128). Block b filters its parent coarse bucket's
// region (parent = b>>2) for sub-bucket (v>>7)&3, histograms + scans 128
// counters, places sorted row-ids in LDS, then runs the quarter-wave uint2
// h-gather. Int LDS atomics only (round 9: fp32 LDS atomics = 15x loss).
// Global spill arena if a fine bucket exceeds CAP.
// ---------------------------------------------------------------------------
__global__ void __launch_bounds__(512) kF_sortagg(
    const unsigned int* __restrict__ EdgeBuf, const int* __restrict__ BucketStart,
    const float* __restrict__ dis, const unsigned short* __restrict__ h,
    const float* __restrict__ b, float* __restrict__ out,
    int* __restrict__ spill, int* __restrict__ spillcur, int n_nodes) {
    __shared__ int cnt[FNPB];
    __shared__ int seg[FNPB];     // inclusive scan
    __shared__ int cursor[FNPB];
    __shared__ int sbuf[CAP];
    __shared__ int sbase_sh;
    int t = threadIdx.x;
    int parent = blockIdx.x >> 2;
    int sub = blockIdx.x & 3;
    int es = BucketStart[parent];
    int ee = BucketStart[parent + 1];
    int nb0 = blockIdx.x << FLOG;

    if (t < FNPB) cnt[t] = 0;
    __syncthreads();
    for (int i = es + t; i < ee; i += 512) {
        unsigned int v = EdgeBuf[i];
        if ((int)((v >> FLOG) & 3u) == sub)
            atomicAdd(&cnt[v & (FNPB - 1)], 1);
    }
    __syncthreads();

    // inclusive scan of cnt into seg (threads 0..127 active; uniform barriers)
    if (t < FNPB) seg[t] = cnt[t];
    __syncthreads();
    for (int off = 1; off < FNPB; off <<= 1) {
        int x = 0;
        if (t < FNPB && t >= off) x = seg[t - off];
        __syncthreads();
        if (t < FNPB) seg[t] += x;
        __syncthreads();
    }
    if (t < FNPB) cursor[t] = seg[t] - cnt[t];
    __syncthreads();

    int ne_f = seg[FNPB - 1];
    if (t == 0 && ne_f > CAP) sbase_sh = atomicAdd(spillcur, ne_f);
    __syncthreads();

    const int lane = t & 63;
    const int wv = t >> 6;          // 0..7
    const int quarter = lane >> 4;  // 0..3
    const int qlane = lane & 15;
    float4 bias = ((const float4*)b)[qlane];

    if (ne_f <= CAP) {
        // ---- place sorted row-ids into LDS (region is L2-hot) ----
        for (int i = es + t; i < ee; i += 512) {
            unsigned int v = EdgeBuf[i];
            if ((int)((v >> FLOG) & 3u) == sub) {
                int p = atomicAdd(&cursor[v & (FNPB - 1)], 1);
                sbuf[p] = (int)(v >> CLOG);
            }
        }
        __syncthreads();

        for (int nl = wv; nl < FNPB; nl += 8) {
            int node = nb0 + nl;
            if (node >= n_nodes) break;
            int e_ = seg[nl];
            int s_ = e_ - cnt[nl];
            float a0 = 0.f, a1 = 0.f, a2 = 0.f, a3 = 0.f;
            for (int j0 = s_; j0 < e_; j0 += 8) {
                int iA = j0 + quarter;
                int iB = j0 + quarter + 4;
                int rA = sbuf[iA < e_ ? iA : s_];   // LDS broadcast read
                int rB = sbuf[iB < e_ ? iB : s_];
                uint2 vA = make_uint2(0u, 0u), vB = make_uint2(0u, 0u);
                if (iA < e_)
                    vA = *(const uint2*)(h + (size_t)rA * OUT_DIM + qlane * 4);
                if (iB < e_)
                    vB = *(const uint2*)(h + (size_t)rB * OUT_DIM + qlane * 4);
                a0 += __uint_as_float(vA.x << 16);
                a1 += __uint_as_float(vA.x & 0xFFFF0000u);
                a2 += __uint_as_float(vA.y << 16);
                a3 += __uint_as_float(vA.y & 0xFFFF0000u);
                a0 += __uint_as_float(vB.x << 16);
                a1 += __uint_as_float(vB.x & 0xFFFF0000u);
                a2 += __uint_as_float(vB.y << 16);
                a3 += __uint_as_float(vB.y & 0xFFFF0000u);
            }
            a0 += __shfl_xor(a0, 16, 64); a0 += __shfl_xor(a0, 32, 64);
            a1 += __shfl_xor(a1, 16, 64); a1 += __shfl_xor(a1, 32, 64);
            a2 += __shfl_xor(a2, 16, 64); a2 += __shfl_xor(a2, 32, 64);
            a3 += __shfl_xor(a3, 16, 64); a3 += __shfl_xor(a3, 32, 64);
            if (quarter == 0) {
                float dv = dis[node];
                float4 o;
                o.x = fmaxf(fmaf(a0, dv, bias.x), 0.f);
                o.y = fmaxf(fmaf(a1, dv, bias.y), 0.f);
                o.z = fmaxf(fmaf(a2, dv, bias.z), 0.f);
                o.w = fmaxf(fmaf(a3, dv, bias.w), 0.f);
                ((float4*)(out + (size_t)node * OUT_DIM))[qlane] = o;
            }
        }
    } else {
        // ---- spill path: sort into a global arena slice ----
        int sbase = sbase_sh;
        for (int i = es + t; i < ee; i += 512) {
            unsigned int v = EdgeBuf[i];
            if ((int)((v >> FLOG) & 3u) == sub) {
                int p = atomicAdd(&cursor[v & (FNPB - 1)], 1);
                spill[sbase + p] = (int)(v >> CLOG);
            }
        }
        __threadfence();
        __syncthreads();
        for (int nl = wv; nl < FNPB; nl += 8) {
            int node = nb0 + nl;
            if (node >= n_nodes) break;
            int e_ = seg[nl];
            int s_ = e_ - cnt[nl];
            float a0 = 0.f, a1 = 0.f, a2 = 0.f, a3 = 0.f;
            for (int j0 = s_; j0 < e_; j0 += 8) {
                int iA = j0 + quarter;
                int iB = j0 + quarter + 4;
                int rA = spill[sbase + (iA < e_ ? iA : s_)];
                int rB = spill[sbase + (iB < e_ ? iB : s_)];
                uint2 vA = make_uint2(0u, 0u), vB = make_uint2(0u, 0u);
                if (iA < e_)
                    vA = *(const uint2*)(h + (size_t)rA * OUT_DIM + qlane * 4);
                if (iB < e_)
                    vB = *(const uint2*)(h + (size_t)rB * OUT_DIM + qlane * 4);
                a0 += __uint_as_float(vA.x << 16);
                a1 += __uint_as_float(vA.x & 0xFFFF0000u);
                a2 += __uint_as_float(vA.y << 16);
                a3 += __uint_as_float(vA.y & 0xFFFF0000u);
                a0 += __uint_as_float(vB.x << 16);
                a1 += __uint_as_float(vB.x & 0xFFFF0000u);
                a2 += __uint_as_float(vB.y << 16);
                a3 += __uint_as_float(vB.y & 0xFFFF0000u);
            }
            a0 += __shfl_xor(a0, 16, 64); a0 += __shfl_xor(a0, 32, 64);
            a1 += __shfl_xor(a1, 16, 64); a1 += __shfl_xor(a1, 32, 64);
            a2 += __shfl_xor(a2, 16, 64); a2 += __shfl_xor(a2, 32, 64);
            a3 += __shfl_xor(a3, 16, 64); a3 += __shfl_xor(a3, 32, 64);
            if (quarter == 0) {
                float dv = dis[node];
                float4 o;
                o.x = fmaxf(fmaf(a0, dv, bias.x), 0.f);
                o.y = fmaxf(fmaf(a1, dv, bias.y), 0.f);
                o.z = fmaxf(fmaf(a2, dv, bias.z), 0.f);
                o.w = fmaxf(fmaf(a3, dv, bias.w), 0.f);
                ((float4*)(out + (size_t)node * OUT_DIM))[qlane] = o;
            }
        }
    }
}

// ---------------------------------------------------------------------------
// Fallback path (exotic sizes / small workspace): atomic scatter, fp32 h
// ---------------------------------------------------------------------------
#define MM_NODES 16
__global__ void __launch_bounds__(256) k_matmul_f32(
    const float* __restrict__ x, const float* __restrict__ W,
    const float* __restrict__ dis, float* __restrict__ h, int n_nodes) {
    __shared__ float xs[MM_NODES * IN_DIM];
    const int lane = threadIdx.x & 63;
    const int wv = threadIdx.x >> 6;
    float w[IN_DIM];
#pragma unroll
    for (int k = 0; k < IN_DIM; ++k) w[k] = W[k * OUT_DIM + lane];
    int nchunks = (n_nodes + MM_NODES - 1) / MM_NODES;
    for (int ch = blockIdx.x; ch < nchunks; ch += gridDim.x) {
        int base = ch * MM_NODES;
        int nrows = min(MM_NODES, n_nodes - base);
        __syncthreads();
        const float4* xg = (const float4*)(x + (size_t)base * IN_DIM);
        int nf4 = nrows * IN_DIM / 4;
        for (int i = threadIdx.x; i < nf4; i += 256) ((float4*)xs)[i] = xg[i];
        __syncthreads();
#pragma unroll
        for (int j = 0; j < 4; ++j) {
            int local = wv * 4 + j;
            int node = base + local;
            if (local < nrows) {
                const float4* xr = (const float4*)(xs + local * IN_DIM);
                float acc = 0.0f;
#pragma unroll
                for (int k4 = 0; k4 < IN_DIM / 4; ++k4) {
                    float4 xv = xr[k4];
                    acc = fmaf(xv.x, w[k4 * 4 + 0], acc);
                    acc = fmaf(xv.y, w[k4 * 4 + 1], acc);
                    acc = fmaf(xv.z, w[k4 * 4 + 2], acc);
                    acc = fmaf(xv.w, w[k4 * 4 + 3], acc);
                }
                h[(size_t)node * OUT_DIM + lane] = acc * dis[node];
            }
        }
    }
}

__global__ void k_degree_fb(const int* __restrict__ col, int* __restrict__ deg,
                            int n_edges) {
    int i = blockIdx.x * blockDim.x + threadIdx.x;
    int stride = gridDim.x * blockDim.x;
    for (; i < n_edges; i += stride) atomicAdd(&deg[col[i]], 1);
}

__global__ void k_rsqrt_fb(const int* __restrict__ deg, float* __restrict__ dis, int n) {
    int i = blockIdx.x * blockDim.x + threadIdx.x;
    if (i < n) {
        int d = deg[i];
        dis[i] = (d > 0) ? rsqrtf((float)d) : 0.0f;
    }
}

__global__ void __launch_bounds__(256) k_scatter_fb(
    const int* __restrict__ row, const int* __restrict__ col,
    const float* __restrict__ dis, const float* __restrict__ h,
    float* __restrict__ out, int n_edges) {
    const int lane = threadIdx.x & 63;
    int e = (blockIdx.x * blockDim.x + threadIdx.x) >> 6;
    int nw = (gridDim.x * blockDim.x) >> 6;
    for (; e < n_edges; e += nw) {
        int r = row[e];
        int c = col[e];
        float v = h[(size_t)r * OUT_DIM + lane] * dis[c];
        atomicAdd(&out[(size_t)c * OUT_DIM + lane], v);
    }
}

__global__ void k_bias_relu_fb(float* __restrict__ out, const float* __restrict__ b,
                               int total) {
    int i = blockIdx.x * blockDim.x + threadIdx.x;
    int stride = gridDim.x * blockDim.x;
    for (; i < total; i += stride) {
        float v = out[i] + b[i & (OUT_DIM - 1)];
        out[i] = fmaxf(v, 0.0f);
    }
}

extern "C" void kernel_launch(void* const* d_in, const int* in_sizes, int n_in,
                              void* d_out, int out_size, void* d_ws, size_t ws_size,
                              hipStream_t stream) {
    const float* x = (const float*)d_in[0];
    const int* ei = (const int*)d_in[1];  // [2, E] int32
    const float* W = (const float*)d_in[2];
    const float* b = (const float*)d_in[3];
    float* out = (float*)d_out;

    const int n_nodes = in_sizes[0] / IN_DIM;
    const int n_edges = in_sizes[1] / 2;
    const int* row = ei;
    const int* col = ei + n_edges;

    const int nbc = (n_nodes + CNPB - 1) >> CLOG;   // coarse buckets
    const int nbf = (n_nodes + FNPB - 1) >> FLOG;   // fine buckets
    const int chunk = (n_edges + B1 - 1) / B1;

    // ---- workspace layout ----
    char* wsb = (char*)d_ws;
    size_t off = 0;
    int* BinTotal = (int*)(wsb + off);   off += align_up((size_t)(nbc + 8) * 4, 256);
    int* spillcur = BinTotal + nbc;      // zeroed by same memset
    int* BucketStart = (int*)(wsb + off);off += align_up((size_t)(nbc + 1) * 4, 256);
    int* tickets = (int*)(wsb + off);    off += align_up((size_t)B1 * nbc * 4, 256);
    float* dis = (float*)(wsb + off);    off += align_up((size_t)n_nodes * 4, 256);
    unsigned int* EdgeBuf = (unsigned int*)(wsb + off);
                                         off += align_up((size_t)n_edges * 4, 256);
    int* spill = (int*)(wsb + off);      off += align_up((size_t)n_edges * 4, 256);
    unsigned short* h = (unsigned short*)(wsb + off);
                                         off += (size_t)n_nodes * OUT_DIM * 2;
    const size_t needed = off;

    const bool ok = (ws_size >= needed) && (nbc <= MAXCOARSE) &&
                    (n_nodes <= (1 << 22));  // row fits in 32-9=23 bits

    if (ok) {
        hipMemsetAsync(BinTotal, 0, (size_t)(nbc + 8) * 4, stream);
        kA_ticket<<<B1, 256, 0, stream>>>(col, BinTotal, tickets, n_edges, nbc,
                                          chunk);
        kS2_scantotals<<<1, 256, 0, stream>>>(BinTotal, BucketStart, nbc, n_edges);
        kB_scatter<<<B1, 256, 0, stream>>>(row, col, BucketStart, tickets, EdgeBuf,
                                           n_edges, nbc, chunk);
        kD_degree<<<nbc, 256, 0, stream>>>(EdgeBuf, BucketStart, dis, n_nodes);
        int ntiles = (n_nodes + 15) / 16;
        int mm_blocks = (ntiles + 3) / 4;
        k_matmul_mfma<<<mm_blocks, 256, 0, stream>>>(x, W, dis, h, n_nodes);
        kF_sortagg<<<nbf, 512, 0, stream>>>(EdgeBuf, BucketStart, dis, h, b,
                                            out, spill, spillcur, n_nodes);
    } else {
        // ---- fallback: atomic scatter, fp32 h ----
        char* p = (char*)d_ws;
        int* deg_f = (int*)p;
        float* dis_f = (float*)(p + align_up((size_t)n_nodes * 4, 256));
        float* h_f = (float*)(p + 2 * align_up((size_t)n_nodes * 4, 256));
        hipMemsetAsync(deg_f, 0, (size_t)n_nodes * 4, stream);
        hipMemsetAsync(out, 0, (size_t)out_size * 4, stream);
        k_degree_fb<<<1024, 256, 0, stream>>>(col, deg_f, n_edges);
        k_rsqrt_fb<<<(n_nodes + 255) / 256, 256, 0, stream>>>(deg_f, dis_f, n_nodes);
        k_matmul_f32<<<1024, 256, 0, stream>>>(x, W, dis_f, h_f, n_nodes);
        k_scatter_fb<<<2048, 256, 0, stream>>>(row, col, dis_f, h_f, out, n_edges);
        k_bias_relu_fb<<<2048, 256, 0, stream>>>(out, b, n_nodes * OUT_DIM);
    }
}